// Round 8
// baseline (155.552 us; speedup 1.0000x reference)
//
#include <hip/hip_runtime.h>

// FeatureVolume: left/right [B=2, H=256, W=256, C=16] f32
// out [B, 2D=48, H, W, 2C=32] f32, s = w - d + 24
// out[b,d,h,w, 0:16] = (0<=s<W) ? left [b,h,w,:] : 0
// out[b,d,h,w,16:32] = (0<=s<W) ? right[b,h,s,:] : 0
//
// R8 = R7 with the nontemporal builtin applied via a native ext_vector_type
// (clang rejects HIP_vector_type<float,4>* as the builtin's pointer arg).
// Structure: 512 blocks=(b,h), register-held left, zero-padded-LDS right,
// marching 32KB/d wave-contiguous nt-stores, ONE barrier.

#define MAXD 24
#define ND   48
#define HH   256
#define WW   256
#define SLICE_F4 (HH * WW * 8)   // 524288 float4 per (b,d) slice

typedef float vf4 __attribute__((ext_vector_type(4)));  // native vec for builtins

__device__ __forceinline__ void nt_store_f4(float4* p, const float4& v) {
    __builtin_nontemporal_store(*reinterpret_cast<const vf4*>(&v),
                                reinterpret_cast<vf4*>(p));
}

__global__ __launch_bounds__(1024, 8) void FeatureVolume_68762426409246_kernel(
    const float4* __restrict__ left,
    const float4* __restrict__ right,
    float4* __restrict__ out) {
    // padded right row: cols -24..279 -> 304 cols x 4 float4 = 1216 f4 (19.5 KB)
    __shared__ float4 rpad[1216];

    const unsigned bh  = blockIdx.x;      // b*HH + h
    const unsigned b   = bh >> 8;
    const unsigned t   = threadIdx.x;     // 0..1023
    const unsigned c4  = t & 7u;          // out-row float4 slot
    const unsigned cc  = t & 3u;          // channel quad within a pixel
    const unsigned wlo = t >> 3;          // 0..127
    const unsigned row = bh << 10;        // input row base (1024 f4/row)
    const float4 Z = make_float4(0.f, 0.f, 0.f, 0.f);

    // zero the pads, stage right row (col s lives at f4 index (24+s)*4+cc)
    if (t < 96u)            rpad[t] = Z;            // cols -24..-1
    else if (t < 192u)      rpad[1024u + t] = Z;    // cols 256..279 (1120..1215)
    rpad[96u + t] = right[row + t];                 // cols 0..255

    const bool isL = (c4 < 4u);
    // left values for this thread's two w slots — only loaded by lanes that
    // use them (c4<4); others keep Z
    float4 L0 = Z, L1 = Z;
    if (isL) {
        L0 = left[row + (wlo << 2) + cc];           // w = wlo
        L1 = left[row + ((wlo + 128u) << 2) + cc];  // w = wlo+128
    }
    __syncthreads();

    const int dmax0 = (int)wlo + MAXD;    // wseg0 left valid iff d <= dmax0
    const int dmin1 = (int)wlo - 103;     // wseg1 left valid iff d >= dmin1

    // LDS cursors for right src col s(d) = wlo+24-d (plus +24 pad offset)
    unsigned a0 = (48u + wlo) * 4u + cc;  // d=0, wseg0
    unsigned a1 = a0 + 512u;              // d=0, wseg1 (s+128)

    // store cursor: f4 index of (b, d=0, h, wlo, c4) = base + t
    float4* op = out + (((size_t)(b * (ND * HH) + (bh & 255u))) << 11) + t;

    float4 r0 = rpad[a0];
    float4 r1 = rpad[a1];
    #pragma unroll 4
    for (int d = 0; d < ND - 1; ++d) {
        a0 -= 4u; a1 -= 4u;
        float4 n0 = rpad[a0];             // prefetch d+1
        float4 n1 = rpad[a1];
        float4 x0 = isL ? ((d <= dmax0) ? L0 : Z) : r0;
        float4 x1 = isL ? ((d >= dmin1) ? L1 : Z) : r1;
        nt_store_f4(op, x0);              // w = wlo       (16 KB burst)
        nt_store_f4(op + 1024, x1);       // w = wlo + 128 (next 16 KB)
        op += SLICE_F4;
        r0 = n0; r1 = n1;
    }
    {   // epilogue d = ND-1 (no prefetch)
        const int d = ND - 1;
        float4 x0 = isL ? ((d <= dmax0) ? L0 : Z) : r0;
        float4 x1 = isL ? ((d >= dmin1) ? L1 : Z) : r1;
        nt_store_f4(op, x0);
        nt_store_f4(op + 1024, x1);
    }
}

extern "C" void kernel_launch(void* const* d_in, const int* in_sizes, int n_in,
                              void* d_out, int out_size, void* d_ws, size_t ws_size,
                              hipStream_t stream) {
    const float4* left  = (const float4*)d_in[0];
    const float4* right = (const float4*)d_in[1];
    float4* out = (float4*)d_out;

    // one block per (b,h): 512 blocks x 1024 threads
    FeatureVolume_68762426409246_kernel<<<2 * HH, 1024, 0, stream>>>(
        left, right, out);
}

// Round 9
// 150.420 us; speedup vs baseline: 1.0341x; 1.0341x over previous
//
#include <hip/hip_runtime.h>

// FeatureVolume: left/right [B=2, H=256, W=256, C=16] f32
// out [B, 2D=48, H, W, 2C=32] f32, s = w - d + 24
// out[b,d,h,w, 0:16] = (0<=s<W) ? left [b,h,w,:] : 0
// out[b,d,h,w,16:32] = (0<=s<W) ? right[b,h,s,:] : 0
//
// FINAL (R6, verified 150.4 us): 512 blocks = (b,h), 1024 threads.
//  - left values register-held (constant across d; left never touches LDS)
//  - right row staged in ZERO-PADDED LDS (cols -24..279) -> right-half
//    boundary masking is free (OOB disparity reads hit pre-zeroed pad)
//  - LDS cursors decrement 64B per d; software-pipelined next-d prefetch
//  - marching wave-contiguous full-line stores (2 x 16 KB per d), ONE barrier
// Session lessons: store streams must be lane-contiguous full-line (R3),
// not fragmented across many regions per unroll (R4); barrier-per-row
// sequential spans lose to barrier-free marching (R5); nt stores null (R8).
// WRITE_SIZE = 786 MB (ideal), FETCH ~20-40 MB (one-pass): ~5.5 TB/s
// effective vs 6.8 TB/s pure-fill ceiling = practical roofline here.

#define MAXD 24
#define ND   48
#define HH   256
#define WW   256
#define SLICE_F4 (HH * WW * 8)   // 524288 float4 per (b,d) slice

__global__ __launch_bounds__(1024, 8) void FeatureVolume_68762426409246_kernel(
    const float4* __restrict__ left,
    const float4* __restrict__ right,
    float4* __restrict__ out) {
    // padded right row: cols -24..279 -> 304 cols x 4 float4 = 1216 f4 (19.5 KB)
    __shared__ float4 rpad[1216];

    const unsigned bh  = blockIdx.x;      // b*HH + h
    const unsigned b   = bh >> 8;
    const unsigned t   = threadIdx.x;     // 0..1023
    const unsigned c4  = t & 7u;          // out-row float4 slot
    const unsigned cc  = t & 3u;          // channel quad within a pixel
    const unsigned wlo = t >> 3;          // 0..127
    const unsigned row = bh << 10;        // input row base (1024 f4/row)
    const float4 Z = make_float4(0.f, 0.f, 0.f, 0.f);

    // zero the pads, stage right row (col s lives at f4 index (24+s)*4+cc)
    if (t < 96u)            rpad[t] = Z;            // cols -24..-1
    else if (t < 192u)      rpad[1024u + t] = Z;    // cols 256..279 (1120..1215)
    rpad[96u + t] = right[row + t];                 // cols 0..255

    // left values for this thread's two w slots (c4>=4 lanes: unused)
    const float4 L0 = left[row + (wlo << 2) + cc];          // w = wlo
    const float4 L1 = left[row + ((wlo + 128u) << 2) + cc]; // w = wlo+128
    __syncthreads();

    const bool isL   = (c4 < 4u);
    const int  dmax0 = (int)wlo + MAXD;   // wseg0 left valid iff d <= dmax0
    const int  dmin1 = (int)wlo - 103;    // wseg1 left valid iff d >= dmin1

    // LDS cursors for right src col s(d) = wlo+24-d (plus +24 pad offset)
    unsigned a0 = (48u + wlo) * 4u + cc;  // d=0, wseg0
    unsigned a1 = a0 + 512u;              // d=0, wseg1 (s+128)

    // store cursor: f4 index of (b, d=0, h, wlo, c4) = base + t
    float4* op = out + (((size_t)(b * (ND * HH) + (bh & 255u))) << 11) + t;

    float4 r0 = rpad[a0];
    float4 r1 = rpad[a1];
    #pragma unroll 4
    for (int d = 0; d < ND - 1; ++d) {
        a0 -= 4u; a1 -= 4u;
        float4 n0 = rpad[a0];             // prefetch d+1
        float4 n1 = rpad[a1];
        float4 x0 = isL ? ((d <= dmax0) ? L0 : Z) : r0;
        float4 x1 = isL ? ((d >= dmin1) ? L1 : Z) : r1;
        op[0]    = x0;                    // w = wlo       (16 KB burst)
        op[1024] = x1;                    // w = wlo + 128 (next 16 KB)
        op += SLICE_F4;
        r0 = n0; r1 = n1;
    }
    {   // epilogue d = ND-1 (no prefetch)
        const int d = ND - 1;
        float4 x0 = isL ? ((d <= dmax0) ? L0 : Z) : r0;
        float4 x1 = isL ? ((d >= dmin1) ? L1 : Z) : r1;
        op[0]    = x0;
        op[1024] = x1;
    }
}

extern "C" void kernel_launch(void* const* d_in, const int* in_sizes, int n_in,
                              void* d_out, int out_size, void* d_ws, size_t ws_size,
                              hipStream_t stream) {
    const float4* left  = (const float4*)d_in[0];
    const float4* right = (const float4*)d_in[1];
    float4* out = (float4*)d_out;

    // one block per (b,h): 512 blocks x 1024 threads
    FeatureVolume_68762426409246_kernel<<<2 * HH, 1024, 0, stream>>>(
        left, right, out);
}